// Round 1
// baseline (105.184 us; speedup 1.0000x reference)
//
#include <hip/hip_runtime.h>
#include <hip/hip_bf16.h>
#include <math.h>

// Problem constants (fixed by reference setup_inputs)
#define BHALF 4096          // B
#define NROW 8192           // 2B
#define DIM 128             // D
#define INV_T 10.0f         // 1/temperature
#define K1 14.4269504088896f  // INV_T*log2(e): exp((v-1)*10) = 2^(v*K1 - K1)

typedef short bf16x8 __attribute__((ext_vector_type(8)));   // 8 bf16 = 4 VGPRs
typedef float f32x4  __attribute__((ext_vector_type(4)));   // C/D frag

// ---------------------------------------------------------------------------
// Kernel 1: row-normalize concat(view1, view2) -> e_bf16 (NROW x DIM);
// zero expsum and d_out. One wave per row.
// ---------------------------------------------------------------------------
__global__ __launch_bounds__(256) void normalize_kernel(
    const float* __restrict__ v1, const float* __restrict__ v2,
    __hip_bfloat16* __restrict__ e, float* __restrict__ expsum,
    float* __restrict__ out) {
  int row  = blockIdx.x * 4 + (threadIdx.x >> 6);
  int lane = threadIdx.x & 63;
  const float* src = (row < BHALF) ? (v1 + (size_t)row * DIM)
                                   : (v2 + (size_t)(row - BHALF) * DIM);
  float2 x = ((const float2*)src)[lane];
  float ss = x.x * x.x + x.y * x.y;
#pragma unroll
  for (int off = 32; off > 0; off >>= 1) ss += __shfl_down(ss, off);
  ss = __shfl(ss, 0);
  float s = 1.0f / fmaxf(sqrtf(ss), 1e-8f);
  ((__hip_bfloat162*)(e + (size_t)row * DIM))[lane] =
      __float22bfloat162_rn(make_float2(x.x * s, x.y * s));
  if (lane == 0) expsum[row] = 0.0f;
  if (blockIdx.x == 0 && threadIdx.x == 0) out[0] = 0.0f;
}

// ---------------------------------------------------------------------------
// Symmetric MFMA sweep over one 128x128 tile (rows: strip r, cols: strip c).
// MODE 0: diagonal tile (r==c): full tile, mask col==row, row-sums only.
// MODE 1: off-diag pair: each exp feeds row-sum AND col-sum (symmetry).
// MODE 2: partner tile (c == r^32): local-diagonal = positives, weight 2
//         (denominator col-0 term + unmasked negative), posv for BOTH rows.
//
// R6 change: NO LDS staging. e is 2 MB -> resident in every XCD L2; the
// per-tile 32 KB B-strip is reused by the block's 4 waves through L1.
// B fragments are read straight from global with a one-sub register
// prefetch (bn). This removes both __syncthreads and the LDS round-trip
// (the 2-phase stage->barrier->compute serialization was the stall).
// NOTE: no per-block device fences anywhere — R5 showed a per-block
// __threadfence costs ~80 ns serialized at TCC (2080 blocks -> +150 us).
// ---------------------------------------------------------------------------
template <int MODE>
__device__ __forceinline__ void sweep_tile(
    const ushort* __restrict__ eB, const bf16x8 (&a_frag)[2][4],
    float (&rsum)[2][4], float* __restrict__ expsum,
    float* __restrict__ posv, int wave, int lane, int n, int quad,
    int rowStrip, int colStrip) {
  const int colBase = colStrip * 128;
  // Per-lane base: row (col of sim) = colBase + sub*16 + n, k-bytes quad*16.
  const ushort* bp = eB + (size_t)n * DIM + quad * 8;
  bf16x8 b[4];
#pragma unroll
  for (int kk = 0; kk < 4; ++kk) b[kk] = *(const bf16x8*)(bp + kk * 32);
#pragma unroll 1
  for (int sub = 0; sub < 8; ++sub) {
    bf16x8 bn[4];
    if (sub < 7) {  // prefetch next sub's B fragments (L1/L2-resident)
      const ushort* bpn = bp + (size_t)(sub + 1) * 16 * DIM;
#pragma unroll
      for (int kk = 0; kk < 4; ++kk) bn[kk] = *(const bf16x8*)(bpn + kk * 32);
    }
    float csum = 0.0f;
    const int lc = sub * 16 + n;
#pragma unroll
    for (int rf = 0; rf < 2; ++rf) {
      f32x4 acc = {0.f, 0.f, 0.f, 0.f};
#pragma unroll
      for (int kk = 0; kk < 4; ++kk)
        acc = __builtin_amdgcn_mfma_f32_16x16x32_bf16(a_frag[rf][kk], b[kk],
                                                      acc, 0, 0, 0);
      // C layout: row = quad*4 + reg, col = lane&15 (m89/m91 verified).
#pragma unroll
      for (int rr = 0; rr < 4; ++rr) {
        const int lr = wave * 32 + rf * 16 + quad * 4 + rr;
        const float val = acc[rr];
        // exp((val-1)/T) = 2^(val*K1 - K1): one v_fma + one v_exp_f32
        const float ex = __builtin_amdgcn_exp2f(val * K1 - K1);
        if (MODE == 0) {
          rsum[rf][rr] += (lr == lc) ? 0.0f : ex;       // mask true diagonal
        } else if (MODE == 1) {
          rsum[rf][rr] += ex;
          csum += ex;
        } else {                                        // partner tile
          const bool hit = (lr == lc);
          const float w = hit ? 2.0f : 1.0f;
          rsum[rf][rr] += w * ex;
          csum += w * ex;
          if (hit) {
            posv[rowStrip * 128 + lr] = val;            // row i
            posv[colBase + lc] = val;                   // partner j = i^4096
          }
        }
      }
    }
    if (MODE != 0) {
      // col-sum: reduce over this wave's 32 rows (across quads), one atomic.
      csum += __shfl_xor(csum, 16);
      csum += __shfl_xor(csum, 32);
      if (lane < 16) atomicAdd(&expsum[colBase + lc], csum);
    }
    if (sub < 7) {
#pragma unroll
      for (int kk = 0; kk < 4; ++kk) b[kk] = bn[kk];
    }
  }
}

// ---------------------------------------------------------------------------
// Kernel 2: symmetric sim + online exp-sum. Grid (64, 33): x = row strip,
// y = cyclic offset d; col strip = (r+d)&63. d=32 valid only for r<32.
// Block: 4 waves; wave w owns rows [r*128 + w*32, +32) with A register-
// resident; B fragments streamed from L1/L2 (no LDS, no barriers).
// ---------------------------------------------------------------------------
__global__ __launch_bounds__(256, 4) void sim_kernel(
    const ushort* __restrict__ e, float* __restrict__ expsum,
    float* __restrict__ posv) {
  const int r = blockIdx.x;
  const int d = blockIdx.y;
  if (d == 32 && r >= 32) return;   // uniform: whole block exits
  const int c = (r + d) & 63;

  const int tid  = threadIdx.x;
  const int wave = tid >> 6;
  const int lane = tid & 63;
  const int n    = lane & 15;
  const int quad = lane >> 4;

  // A fragments: 2 row-frags x 4 k-steps, register-resident.
  bf16x8 a_frag[2][4];
  const int rowWave = r * 128 + wave * 32;
#pragma unroll
  for (int rf = 0; rf < 2; ++rf) {
    const ushort* rp = e + (size_t)(rowWave + rf * 16 + n) * DIM + quad * 8;
#pragma unroll
    for (int kk = 0; kk < 4; ++kk)
      a_frag[rf][kk] = *(const bf16x8*)(rp + kk * 32);
  }

  float rsum[2][4] = {{0.f, 0.f, 0.f, 0.f}, {0.f, 0.f, 0.f, 0.f}};
  const ushort* eB = e + (size_t)c * 128 * DIM;

  if (d == 0)
    sweep_tile<0>(eB, a_frag, rsum, expsum, posv, wave, lane, n, quad, r, c);
  else if (d == 32)
    sweep_tile<2>(eB, a_frag, rsum, expsum, posv, wave, lane, n, quad, r, c);
  else
    sweep_tile<1>(eB, a_frag, rsum, expsum, posv, wave, lane, n, quad, r, c);

  // Row sums: reduce across the 16 col-lanes, one atomic per row.
#pragma unroll
  for (int rf = 0; rf < 2; ++rf)
#pragma unroll
    for (int rr = 0; rr < 4; ++rr) {
      float v = rsum[rf][rr];
      v += __shfl_xor(v, 1);
      v += __shfl_xor(v, 2);
      v += __shfl_xor(v, 4);
      v += __shfl_xor(v, 8);
      if (n == 0) atomicAdd(&expsum[rowWave + rf * 16 + quad * 4 + rr], v);
    }
}

// ---------------------------------------------------------------------------
// Kernel 3: loss_i = log(S_i) + (1 - pos_i)/T ; out = mean (atomic partials).
// 32 blocks x 256 threads, one row per thread.
// ---------------------------------------------------------------------------
__global__ __launch_bounds__(256) void finalize_kernel(
    const float* __restrict__ expsum, const float* __restrict__ posv,
    float* __restrict__ out) {
  __shared__ float red[4];
  const int i = blockIdx.x * 256 + threadIdx.x;
  float l = __logf(expsum[i]) + (1.0f - posv[i]) * INV_T;
#pragma unroll
  for (int off = 32; off > 0; off >>= 1) l += __shfl_down(l, off);
  if ((threadIdx.x & 63) == 0) red[threadIdx.x >> 6] = l;
  __syncthreads();
  if (threadIdx.x == 0)
    atomicAdd(out, (red[0] + red[1] + red[2] + red[3]) * (1.0f / NROW));
}

// ---------------------------------------------------------------------------
extern "C" void kernel_launch(void* const* d_in, const int* in_sizes, int n_in,
                              void* d_out, int out_size, void* d_ws, size_t ws_size,
                              hipStream_t stream) {
  const float* v1 = (const float*)d_in[0];
  const float* v2 = (const float*)d_in[1];
  float* out = (float*)d_out;

  __hip_bfloat16* e = (__hip_bfloat16*)d_ws;          // NROW*DIM bf16 (2 MB)
  float* expsum = (float*)(e + (size_t)NROW * DIM);   // NROW floats
  float* posv   = expsum + NROW;                      // NROW floats

  normalize_kernel<<<NROW / 4, 256, 0, stream>>>(v1, v2, e, expsum, out);
  dim3 grid(64, 33);
  sim_kernel<<<grid, 256, 0, stream>>>((const ushort*)e, expsum, posv);
  finalize_kernel<<<32, 256, 0, stream>>>(expsum, posv, out);
}

// Round 2
// 86.316 us; speedup vs baseline: 1.2186x; 1.2186x over previous
//
#include <hip/hip_runtime.h>
#include <hip/hip_bf16.h>
#include <math.h>

// Problem constants (fixed by reference setup_inputs)
#define BHALF 4096          // B
#define NROW 8192           // 2B
#define DIM 128             // D
#define NCHUNK 8            // col chunks per row strip (8 strips of 128 cols each)
#define INV_T 10.0f         // 1/temperature
#define K1 14.4269504088896f  // INV_T*log2(e): exp((v-1)*10) = 2^(v*K1 - K1)

typedef short bf16x8 __attribute__((ext_vector_type(8)));   // 8 bf16 = 4 VGPRs
typedef float f32x4  __attribute__((ext_vector_type(4)));   // C/D frag

typedef const __attribute__((address_space(1))) void ga_void;
typedef __attribute__((address_space(3))) void ls_void;

// ---------------------------------------------------------------------------
// Kernel 1: row-normalize concat(view1, view2) -> e_bf16 (NROW x DIM);
// zero d_out. One wave per row.
// ---------------------------------------------------------------------------
__global__ __launch_bounds__(256) void normalize_kernel(
    const float* __restrict__ v1, const float* __restrict__ v2,
    __hip_bfloat16* __restrict__ e, float* __restrict__ out) {
  int row  = blockIdx.x * 4 + (threadIdx.x >> 6);
  int lane = threadIdx.x & 63;
  const float* src = (row < BHALF) ? (v1 + (size_t)row * DIM)
                                   : (v2 + (size_t)(row - BHALF) * DIM);
  float2 x = ((const float2*)src)[lane];
  float ss = x.x * x.x + x.y * x.y;
#pragma unroll
  for (int off = 32; off > 0; off >>= 1) ss += __shfl_down(ss, off);
  ss = __shfl(ss, 0);
  float s = 1.0f / fmaxf(sqrtf(ss), 1e-8f);
  ((__hip_bfloat162*)(e + (size_t)row * DIM))[lane] =
      __float22bfloat162_rn(make_float2(x.x * s, x.y * s));
  if (blockIdx.x == 0 && threadIdx.x == 0) out[0] = 0.0f;
}

// ---------------------------------------------------------------------------
// Stage one 128x128-col strip of e into LDS buffer via global_load_lds.
// LDS layout: row-major [128 rows][16 chunks of 16B], with the chunk index
// XOR-swizzled by (row&7) so that ds_read_b128 of a fixed global chunk
// across 16 consecutive rows spreads over 8 bank-quads (conflict-free).
// Rule #21: LDS dest is LINEAR (base + lane*16); the swizzle is applied by
// permuting the per-lane GLOBAL source chunk (XOR is an involution).
// Each wave stages its own 32 rows (8 segments x 4 rows x 256B).
// ---------------------------------------------------------------------------
__device__ __forceinline__ void stage_strip(const ushort* __restrict__ eC,
                                            ushort* BsBuf, int wave, int lane) {
#pragma unroll
  for (int j = 0; j < 8; ++j) {
    const int row    = wave * 32 + j * 4 + (lane >> 4);
    const int chunkp = lane & 15;                 // LDS chunk this lane fills
    const int gchunk = chunkp ^ (row & 7);        // global chunk it must hold
    const ushort* g  = eC + row * DIM + gchunk * 8;
    ushort* l        = BsBuf + (wave * 32 + j * 4) * 128;  // wave-uniform base
    __builtin_amdgcn_global_load_lds((ga_void*)g, (ls_void*)l, 16, 0, 0);
  }
}

// ---------------------------------------------------------------------------
// MFMA sweep over one 128x128 tile held in LDS (rows: strip r, cols: strip c).
// MODE 0: diagonal strip (c==r): mask col==row (self-similarity).
// MODE 1: plain strip: accumulate row sums.
// MODE 2: partner strip (c==r^32): local diagonal = positives -> posv store.
// No atomics: rsum is register-resident for the block's own 128 rows.
// ---------------------------------------------------------------------------
template <int MODE>
__device__ __forceinline__ void sweep_strip(
    const ushort* __restrict__ Bs, const bf16x8 (&a_frag)[2][4],
    float (&rsum)[2][4], float* __restrict__ posv, const int (&chunkOff)[4],
    int wave, int n, int quad, int rowBase) {
#pragma unroll 1
  for (int sub = 0; sub < 8; ++sub) {
    const ushort* bp = Bs + (sub * 16 + n) * 128;
    bf16x8 b[4];
#pragma unroll
    for (int kk = 0; kk < 4; ++kk) b[kk] = *(const bf16x8*)(bp + chunkOff[kk]);
    const int lc = sub * 16 + n;
#pragma unroll
    for (int rf = 0; rf < 2; ++rf) {
      f32x4 acc = {0.f, 0.f, 0.f, 0.f};
#pragma unroll
      for (int kk = 0; kk < 4; ++kk)
        acc = __builtin_amdgcn_mfma_f32_16x16x32_bf16(a_frag[rf][kk], b[kk],
                                                      acc, 0, 0, 0);
      // C layout: row = quad*4 + reg, col = lane&15 (m89/m91 verified).
#pragma unroll
      for (int rr = 0; rr < 4; ++rr) {
        const int lr = wave * 32 + rf * 16 + quad * 4 + rr;
        const float val = acc[rr];
        // exp((val-1)/T) = 2^(val*K1 - K1): one v_fma + one v_exp_f32
        const float ex = __builtin_amdgcn_exp2f(val * K1 - K1);
        if (MODE == 0) {
          rsum[rf][rr] += (lr == lc) ? 0.0f : ex;   // mask true diagonal
        } else if (MODE == 2) {
          rsum[rf][rr] += ex;                       // positive counted once
          if (lr == lc) posv[rowBase + lr] = val;   // record positive sim
        } else {
          rsum[rf][rr] += ex;
        }
      }
    }
  }
}

// ---------------------------------------------------------------------------
// Kernel 2: full-matrix sim + exp row-sums, zero atomics.
// Grid (NCHUNK=8, 64): x = col chunk g (strips g*8..g*8+7), y = row strip r.
// 512 blocks = exactly 2 blocks/CU (LDS-bound), one round, no tail.
// Block: 4 waves; wave w owns rows [r*128 + w*32, +32), A register-resident.
// B strips double-buffered in LDS (2 x 32 KB), staged by global_load_lds;
// __syncthreads() per strip drains vmcnt (compiler emits the full waitcnt).
// Row sums -> direct store to partial[g*NROW + row]; finalize sums 8 chunks.
// ---------------------------------------------------------------------------
__global__ __launch_bounds__(256, 2) void sim_kernel(
    const ushort* __restrict__ e, float* __restrict__ partial,
    float* __restrict__ posv) {
  const int g = blockIdx.x;
  const int r = blockIdx.y;

  __shared__ ushort Bs[2][128 * 128] __attribute__((aligned(16)));

  const int tid  = threadIdx.x;
  const int wave = tid >> 6;
  const int lane = tid & 63;
  const int n    = lane & 15;
  const int quad = lane >> 4;

  // Per-lane swizzled LDS chunk offsets (ushort units), static per kernel:
  // global chunk (quad + 4*kk) of row (..n) lives at chunk ^ (n&7).
  int chunkOff[4];
#pragma unroll
  for (int kk = 0; kk < 4; ++kk)
    chunkOff[kk] = (((quad + 4 * kk) ^ (n & 7)) * 8);

  // A fragments: 2 row-frags x 4 k-steps, register-resident.
  bf16x8 a_frag[2][4];
  const int rowWave = r * 128 + wave * 32;
#pragma unroll
  for (int rf = 0; rf < 2; ++rf) {
    const ushort* rp = e + (size_t)(rowWave + rf * 16 + n) * DIM + quad * 8;
#pragma unroll
    for (int kk = 0; kk < 4; ++kk)
      a_frag[rf][kk] = *(const bf16x8*)(rp + kk * 32);
  }

  // Special strips within this chunk: diagonal (c==r) and partner (c==r^32).
  const int sDiag = ((r >> 3) == g) ? (r & 7) : -1;
  const int sPart = (((r ^ 32) >> 3) == g) ? (r & 7) : -1;  // (r^32)&7 == r&7

  float rsum[2][4] = {{0.f, 0.f, 0.f, 0.f}, {0.f, 0.f, 0.f, 0.f}};

  // Prologue: stage strip 0.
  stage_strip(e + (size_t)(g * 8) * 128 * DIM, Bs[0], wave, lane);
  __syncthreads();

#pragma unroll 1
  for (int s = 0; s < 8; ++s) {
    if (s < 7)  // issue next strip's DMA before compute (loads fly under MFMA)
      stage_strip(e + (size_t)(g * 8 + s + 1) * 128 * DIM, Bs[(s + 1) & 1],
                  wave, lane);
    const ushort* buf = Bs[s & 1];
    if (s == sDiag)
      sweep_strip<0>(buf, a_frag, rsum, posv, chunkOff, wave, n, quad, r * 128);
    else if (s == sPart)
      sweep_strip<2>(buf, a_frag, rsum, posv, chunkOff, wave, n, quad, r * 128);
    else
      sweep_strip<1>(buf, a_frag, rsum, posv, chunkOff, wave, n, quad, r * 128);
    if (s < 7) __syncthreads();  // drains vmcnt(0): next buffer ready
  }

  // Row sums: reduce across the 16 col-lanes, direct store (no atomics).
#pragma unroll
  for (int rf = 0; rf < 2; ++rf)
#pragma unroll
    for (int rr = 0; rr < 4; ++rr) {
      float v = rsum[rf][rr];
      v += __shfl_xor(v, 1);
      v += __shfl_xor(v, 2);
      v += __shfl_xor(v, 4);
      v += __shfl_xor(v, 8);
      if (n == 0)
        partial[g * NROW + rowWave + rf * 16 + quad * 4 + rr] = v;
    }
}

// ---------------------------------------------------------------------------
// Kernel 3: S_i = sum_g partial[g][i]; loss_i = log(S_i + exp((pos-1)/T))
//           + (1-pos_i)/T ; out = mean (atomic partials).
// ---------------------------------------------------------------------------
__global__ __launch_bounds__(256) void finalize_kernel(
    const float* __restrict__ partial, const float* __restrict__ posv,
    float* __restrict__ out) {
  __shared__ float red[4];
  const int i = blockIdx.x * 256 + threadIdx.x;
  float S = 0.0f;
#pragma unroll
  for (int gg = 0; gg < NCHUNK; ++gg) S += partial[gg * NROW + i];
  const float p = posv[i];
  const float l =
      __logf(S + __builtin_amdgcn_exp2f(p * K1 - K1)) + (1.0f - p) * INV_T;
  float v = l;
#pragma unroll
  for (int off = 32; off > 0; off >>= 1) v += __shfl_down(v, off);
  if ((threadIdx.x & 63) == 0) red[threadIdx.x >> 6] = v;
  __syncthreads();
  if (threadIdx.x == 0)
    atomicAdd(out, (red[0] + red[1] + red[2] + red[3]) * (1.0f / NROW));
}

// ---------------------------------------------------------------------------
extern "C" void kernel_launch(void* const* d_in, const int* in_sizes, int n_in,
                              void* d_out, int out_size, void* d_ws, size_t ws_size,
                              hipStream_t stream) {
  const float* v1 = (const float*)d_in[0];
  const float* v2 = (const float*)d_in[1];
  float* out = (float*)d_out;

  __hip_bfloat16* e = (__hip_bfloat16*)d_ws;          // NROW*DIM bf16 (2 MB)
  float* partial = (float*)(e + (size_t)NROW * DIM);  // NCHUNK*NROW floats
  float* posv    = partial + (size_t)NCHUNK * NROW;   // NROW floats

  normalize_kernel<<<NROW / 4, 256, 0, stream>>>(v1, v2, e, out);
  dim3 grid(NCHUNK, 64);
  sim_kernel<<<grid, 256, 0, stream>>>((const ushort*)e, partial, posv);
  finalize_kernel<<<32, 256, 0, stream>>>(partial, posv, out);
}